// Round 1
// 823.128 us; speedup vs baseline: 1.0022x; 1.0022x over previous
//
#include <hip/hip_runtime.h>

// URPE: out[b,h,i,j] = attn[b,h,i,j] * toe(h, i, j)
// toe(h,i,j) = (j >= i) ? w[h, L + j - i] : w[h, i - j]
// B=2, H=16, L=2048 -> attn is 512 MiB fp32; pure memory-bound multiply.
//
// toe is independent of b, so each block handles BOTH batch elements for its
// (h, i) row: halves the w-gather VMEM ops and doubles streaming bytes in
// flight per thread (2x float4 load + 2x float4 store).

#define URPE_B 2
#define URPE_H 16
#define URPE_L 2048

__global__ __launch_bounds__(512) void urpe_mul_kernel(
    const float* __restrict__ attn,
    const float* __restrict__ w,
    float* __restrict__ out)
{
    const int i = blockIdx.x;             // query position (row), [0, L)
    const int h = blockIdx.y;             // head, [0, H)

    const float* __restrict__ wh = w + (size_t)h * (2 * URPE_L);

    const int j0 = threadIdx.x << 2;      // 512 threads * 4 floats = 2048 = L

    const size_t base0   = ((size_t)h * URPE_L + (size_t)i) * URPE_L + j0;     // b = 0
    const size_t bstride = (size_t)URPE_H * URPE_L * URPE_L;                   // b = 1 offset

    // Issue both streaming loads first: 32 B in flight per thread.
    float4 a0 = *reinterpret_cast<const float4*>(attn + base0);
    float4 a1 = *reinterpret_cast<const float4*>(attn + base0 + bstride);

    // w gather (L1-resident, 16 KiB working set per head), shared by both b.
    int j = j0;
    float w0 = (j >= i) ? wh[URPE_L + j - i] : wh[i - j]; ++j;
    float w1 = (j >= i) ? wh[URPE_L + j - i] : wh[i - j]; ++j;
    float w2 = (j >= i) ? wh[URPE_L + j - i] : wh[i - j]; ++j;
    float w3 = (j >= i) ? wh[URPE_L + j - i] : wh[i - j];

    float4 o0, o1;
    o0.x = a0.x * w0;  o0.y = a0.y * w1;  o0.z = a0.z * w2;  o0.w = a0.w * w3;
    o1.x = a1.x * w0;  o1.y = a1.y * w1;  o1.z = a1.z * w2;  o1.w = a1.w * w3;

    *reinterpret_cast<float4*>(out + base0) = o0;
    *reinterpret_cast<float4*>(out + base0 + bstride) = o1;
}

extern "C" void kernel_launch(void* const* d_in, const int* in_sizes, int n_in,
                              void* d_out, int out_size, void* d_ws, size_t ws_size,
                              hipStream_t stream)
{
    const float* attn = (const float*)d_in[0];   // (B, H, L, L) fp32
    const float* w    = (const float*)d_in[1];   // (H, 2L) fp32
    float* out        = (float*)d_out;           // (B, H, L, L) fp32

    dim3 grid(URPE_L, URPE_H);                   // one block per (i, h); covers b=0,1
    urpe_mul_kernel<<<grid, 512, 0, stream>>>(attn, w, out);
}